// Round 9
// baseline (17671.472 us; speedup 1.0000x reference)
//
#include <hip/hip_runtime.h>
#include <float.h>
#include <math.h>

// ---------------- problem constants ----------------
#define M_ROWS 6272        // 8*28*28 rows of f
#define N_BANK 16384
#define K_DIM  1024
#define HW     784         // 28*28
#define CHW    802816      // 1024*784 (per-batch stride in features)
#define OUT_NORM_OFF 6422528
#define OUT_STD_OFF  6428800
#define N_ELEMS 6422528    // 6272*1024

// f32-scan ambiguity margin on d^2
#define DELTA 0.0625f

// RNG layout history (error ~2.7-3.1 floor => wrong):
//   legacy split-halves (i, i+N/2)->o0/o1   (r1-3): 2.6875
//   partitionable (0,e) o1                  (r4):   2.7539
//   partitionable (0,e) o0                  (r5):   2.6875
//   partitionable (e,0) o1                  (r6):   2.6875
//   partitionable (e,0) o0                  (r7):   2.9014
//   two-per-block (0,e>>1) even:o0/odd:o1   (r8):   3.1328   [KATs passed: core+transform OK]
// This round: partitionable (0,e), bits = o0 ^ o1   (jax bit_width==32: bits1 ^ bits2)

// scratch (float offsets in d_out's noised region; consumed before noise kernel)
#define WS_SIDX 0          // 6272 ints
#define WS_FLAG 8192       // 6272 ints
#define WS_INFL 16384      // 6272 doubles
#define WS_MM   32768      // 2 doubles

// ---------------- threefry2x32-20, generalized key ----------------
__device__ __forceinline__ unsigned rotl32(unsigned v, int r){ return (v << r) | (v >> (32 - r)); }

__device__ __forceinline__ void tf2x32(unsigned k0, unsigned k1, unsigned x0, unsigned x1,
                                       unsigned& o0, unsigned& o1){
  const unsigned ks2 = k0 ^ k1 ^ 0x1BD11BDAu;
  x0 += k0; x1 += k1;
#define TF_ROUND(rot) { x0 += x1; x1 = rotl32(x1, rot); x1 ^= x0; }
  TF_ROUND(13) TF_ROUND(15) TF_ROUND(26) TF_ROUND(6)
  x0 += k1;  x1 += ks2 + 1u;
  TF_ROUND(17) TF_ROUND(29) TF_ROUND(16) TF_ROUND(24)
  x0 += ks2; x1 += k0 + 2u;
  TF_ROUND(13) TF_ROUND(15) TF_ROUND(26) TF_ROUND(6)
  x0 += k0;  x1 += k1 + 3u;
  TF_ROUND(17) TF_ROUND(29) TF_ROUND(16) TF_ROUND(24)
  x0 += k1;  x1 += ks2 + 4u;
  TF_ROUND(13) TF_ROUND(15) TF_ROUND(26) TF_ROUND(6)
  x0 += ks2; x1 += k0 + 5u;
#undef TF_ROUND
  o0 = x0; o1 = x1;
}

// JAX uniform-from-bits + XLA ErfInv32 (Giles), scaled by sqrt(2)
__device__ __forceinline__ float normal_from_bits(unsigned bits){
  unsigned fb = (bits >> 9) | 0x3F800000u;
  float f = __uint_as_float(fb) - 1.0f;            // [0, 1)
  const float lo = __uint_as_float(0xBF7FFFFFu);   // nextafter(-1,0)
  float u = fmaxf(lo, f * 2.0f + lo);
  float w = -log1pf(-u * u);
  float p;
  if (w < 5.0f){
    w = w - 2.5f;
    p = 2.81022636e-08f;
    p = fmaf(p, w, 3.43273939e-07f);
    p = fmaf(p, w, -3.5233877e-06f);
    p = fmaf(p, w, -4.39150654e-06f);
    p = fmaf(p, w, 0.00021858087f);
    p = fmaf(p, w, -0.00125372503f);
    p = fmaf(p, w, -0.00417768164f);
    p = fmaf(p, w, 0.246640727f);
    p = fmaf(p, w, 1.50140941f);
  } else {
    w = sqrtf(w) - 3.0f;
    p = -0.000200214257f;
    p = fmaf(p, w, 0.000100950558f);
    p = fmaf(p, w, 0.00134934322f);
    p = fmaf(p, w, -0.00367342844f);
    p = fmaf(p, w, 0.00573950773f);
    p = fmaf(p, w, -0.0076224613f);
    p = fmaf(p, w, 0.00943887047f);
    p = fmaf(p, w, 1.00167406f);
    p = fmaf(p, w, 2.83297682f);
  }
  return 1.41421356237f * (p * u);
}

// ---------------- kernel A: f32 argmin scan with top-2 margin, 4 rows/wave ----------------
__global__ __launch_bounds__(256) void scan_kernel(
    const float* __restrict__ feat, const float* __restrict__ mb,
    int* __restrict__ sidx, int* __restrict__ flag)
{
  const int wave = (blockIdx.x * 256 + threadIdx.x) >> 6;
  const int lane = threadIdx.x & 63;
  const int r0 = wave * 4;

  float fr[4][16];
  float fn2[4];
#pragma unroll
  for (int q = 0; q < 4; ++q){
    const int r = r0 + q;
    const int b = r / HW;
    const int hw = r - b * HW;
    const float* fbase = feat + b * CHW + hw;
#pragma unroll
    for (int i = 0; i < 4; ++i)
#pragma unroll
      for (int m = 0; m < 4; ++m)
        fr[q][i*4+m] = fbase[(i*256 + lane*4 + m) * HW];
    float s = 0.f;
#pragma unroll
    for (int x = 0; x < 16; ++x) s = fmaf(fr[q][x], fr[q][x], s);
#pragma unroll
    for (int off = 1; off < 64; off <<= 1) s += __shfl_xor(s, off);
    fn2[q] = s;
  }

  float best[4] = {FLT_MAX, FLT_MAX, FLT_MAX, FLT_MAX};
  float sec[4]  = {FLT_MAX, FLT_MAX, FLT_MAX, FLT_MAX};
  int   bidx[4] = {0, 0, 0, 0};

  for (int j = 0; j < N_BANK; ++j){
    const float* mrow = mb + (size_t)j * K_DIM + lane * 4;
    float m2 = 0.f, d0 = 0.f, d1 = 0.f, d2_ = 0.f, d3 = 0.f;
#pragma unroll
    for (int i = 0; i < 4; ++i){
      const float4 mv = *reinterpret_cast<const float4*>(mrow + i*256);
      const float mvv[4] = {mv.x, mv.y, mv.z, mv.w};
#pragma unroll
      for (int m = 0; m < 4; ++m){
        const float v = mvv[m];
        m2  = fmaf(v, v, m2);
        d0  = fmaf(fr[0][i*4+m], v, d0);
        d1  = fmaf(fr[1][i*4+m], v, d1);
        d2_ = fmaf(fr[2][i*4+m], v, d2_);
        d3  = fmaf(fr[3][i*4+m], v, d3);
      }
    }
    float s0 = fmaf(-2.f, d0, m2);
    float s1 = fmaf(-2.f, d1, m2);
    float s2 = fmaf(-2.f, d2_, m2);
    float s3 = fmaf(-2.f, d3, m2);
#pragma unroll
    for (int off = 1; off < 64; off <<= 1){
      s0 += __shfl_xor(s0, off);
      s1 += __shfl_xor(s1, off);
      s2 += __shfl_xor(s2, off);
      s3 += __shfl_xor(s3, off);
    }
    float v[4] = {fn2[0]+s0, fn2[1]+s1, fn2[2]+s2, fn2[3]+s3};
#pragma unroll
    for (int q = 0; q < 4; ++q){
      if (v[q] < best[q]){ sec[q] = best[q]; best[q] = v[q]; bidx[q] = j; }
      else if (v[q] < sec[q]){ sec[q] = v[q]; }
    }
  }

  if (lane == 0){
#pragma unroll
    for (int q = 0; q < 4; ++q){
      sidx[r0 + q] = bidx[q];
      flag[r0 + q] = (sec[q] - best[q] < DELTA) ? 1 : 0;
    }
  }
}

// ---------------- kernel B: f64 full re-scan for ambiguous rows ----------------
__global__ __launch_bounds__(256) void refine_kernel(
    const float* __restrict__ feat, const float* __restrict__ mb,
    const int* __restrict__ flag, int* __restrict__ sidx)
{
  const int r = blockIdx.x;
  if (!flag[r]) return;
  __shared__ float fs[K_DIM];
  const int b = r / HW, hw = r - b * HW;
  for (int c = threadIdx.x; c < K_DIM; c += 256) fs[c] = feat[b * CHW + c * HW + hw];
  __syncthreads();

  double bestv = DBL_MAX; int bi = N_BANK - 1;
  for (int j = threadIdx.x; j < N_BANK; j += 256){
    const float* mrow = mb + (size_t)j * K_DIM;
    double s = 0.0;
#pragma unroll 8
    for (int c = 0; c < K_DIM; ++c){
      double d = (double)fs[c] - (double)mrow[c];
      s = fma(d, d, s);
    }
    if (s < bestv){ bestv = s; bi = j; }
  }
  __shared__ double rv[256]; __shared__ int ri[256];
  rv[threadIdx.x] = bestv; ri[threadIdx.x] = bi; __syncthreads();
  for (int off = 128; off; off >>= 1){
    if (threadIdx.x < off){
      double v2 = rv[threadIdx.x + off]; int i2 = ri[threadIdx.x + off];
      if (v2 < rv[threadIdx.x] || (v2 == rv[threadIdx.x] && i2 < ri[threadIdx.x])){
        rv[threadIdx.x] = v2; ri[threadIdx.x] = i2;
      }
    }
    __syncthreads();
  }
  if (threadIdx.x == 0) sidx[r] = ri[0];
}

// ---------------- kernel C: f64 influence from the winner ----------------
__global__ __launch_bounds__(256) void influence_kernel(
    const float* __restrict__ feat, const float* __restrict__ mb,
    const int* __restrict__ sidx, double* __restrict__ infl)
{
  const int wid  = (blockIdx.x * 256 + threadIdx.x) >> 6;
  const int lane = threadIdx.x & 63;
  if (wid >= M_ROWS) return;
  const int r = wid;
  const int b = r / HW;
  const int baseR = b * CHW + (r - b * HW);
  const float* mrow = mb + (size_t)sidx[r] * K_DIM;
  double sabs = 0.0, sd2 = 0.0;
#pragma unroll
  for (int i = 0; i < 16; ++i){
    int c = lane + i*64;
    double d = (double)feat[baseR + c * HW] - (double)mrow[c];
    sd2  = fma(d, d, sd2);
    sabs += fabs(d);
  }
#pragma unroll
  for (int off = 1; off < 64; off <<= 1){
    sabs += __shfl_xor(sabs, off);
    sd2  += __shfl_xor(sd2, off);
  }
  if (lane == 0){
    double dist = sqrt(fmax(sd2, 0.0) + 1e-8);
    infl[r] = (sabs / 1024.0) / (dist + 1e-8);
  }
}

// ---------------- kernel D: f64 global min/max ----------------
__global__ __launch_bounds__(1024) void minmax_kernel(const double* __restrict__ infl, double* __restrict__ mm){
  __shared__ double smn[1024], smx[1024];
  int t = threadIdx.x;
  double mn = DBL_MAX, mx = -DBL_MAX;
  for (int i = t; i < M_ROWS; i += 1024){ double v = infl[i]; mn = fmin(mn, v); mx = fmax(mx, v); }
  smn[t] = mn; smx[t] = mx; __syncthreads();
  for (int off = 512; off > 0; off >>= 1){
    if (t < off){ smn[t] = fmin(smn[t], smn[t+off]); smx[t] = fmax(smx[t], smx[t+off]); }
    __syncthreads();
  }
  if (t == 0){ mm[0] = smn[0]; mm[1] = smx[0]; }
}

// ---------------- kernel E: f64 norm + std -> f32 outputs; stash mm into d_ws ----------------
__global__ __launch_bounds__(256) void normstd_kernel(
    const double* __restrict__ mm, const double* __restrict__ infl,
    float* __restrict__ norm_out, float* __restrict__ std_out, double* __restrict__ dws)
{
  int r = blockIdx.x * blockDim.x + threadIdx.x;
  if (r >= M_ROWS) return;
  double imin = mm[0], imax = mm[1];
  if (r == 0){ dws[0] = imin; dws[1] = imax; }
  double rng = imax - imin;
  double nrm = (rng > 1e-8) ? (infl[r] - imin) / rng : 0.0;
  norm_out[r] = (float)nrm;
  std_out[r]  = (float)(0.01 + nrm * 0.49);
}

// ---------------- kernel F: noise — partitionable (0,e), bits = o0 ^ o1 ----------------
__global__ __launch_bounds__(256) void noise_kernel(
    const float* __restrict__ feat, const float* __restrict__ stds, float* __restrict__ out)
{
  int tid = blockIdx.x * 256 + threadIdx.x;     // BCHW address
  int b   = tid / CHW;
  int rem = tid - b * CHW;
  int c   = rem / HW;
  int hw  = rem - c * HW;
  int r   = b * HW + hw;                        // row in (6272, 1024) view
  unsigned e = (unsigned)r * (unsigned)K_DIM + (unsigned)c;
  unsigned o0, o1;
  tf2x32(0u, 1u, 0u, e, o0, o1);
  unsigned bits = o0 ^ o1;                      // jax partitionable, bit_width==32
  float n = normal_from_bits(bits);
  out[tid] = feat[tid] + n * stds[r];
}

// ---------------- kernel G: diagnostic verdict (sigma stats; inert when in-band) ----------------
__global__ void diag_kernel(const double* __restrict__ dws, float* __restrict__ out){
  double imin = dws[0], imax = dws[1];
  double rng = imax - imin;
  double code = 0.0, payload = 0.0;
  if (!(imin == imin) || !(imax == imax)){ code = 5e6; }
  else if (rng <= 1e-8){ code = 1e6; payload = fmin(fmax(rng, 0.0) * 1e12, 9e5); }
  else if (imax > 0.5){ code = 2e6; payload = fmin(imax * 1e4, 9e5); }
  else if (imin <= 1e-4){ code = 3e6; payload = fmin(fmax(imin, 0.0) * 1e6, 9e5); }
  else if (imax > 10.0 * imin){ code = 4e6; payload = fmin(imax * 1e4, 9e5); }
  if (code > 0.0) out[0] = (float)(code + payload);
}

// ---------------- kernel H: on-device known-answer tests (verified passing in r8) ----------
__global__ void kat_kernel(float* __restrict__ out){
  float code = 0.f;
  unsigned a, b;
  tf2x32(0u, 0u, 0u, 0u, a, b);
  if (a != 0x6b200159u || b != 0x99ba4efeu) code = 1e10f;
  unsigned c2, d2;
  tf2x32(0x13198a2eu, 0x03707344u, 0x243f6a88u, 0x85a308d3u, c2, d2);
  if (code == 0.f && (c2 != 0xc4923a9cu || d2 != 0x483df7a0u)) code = 3e9f;
  float n = normal_from_bits(0x6b200159u);
  if (code == 0.f && fabsf(n - (-0.20584226f)) > 2e-5f) code = 1e9f;
  if (code > 0.f) out[0] = code;
}

extern "C" void kernel_launch(void* const* d_in, const int* in_sizes, int n_in,
                              void* d_out, int out_size, void* d_ws, size_t ws_size,
                              hipStream_t stream) {
  const float* feat = (const float*)d_in[0];
  const float* mb   = (const float*)d_in[1];
  float* out = (float*)d_out;

  int*    sidx = (int*)(out + WS_SIDX);
  int*    flag = (int*)(out + WS_FLAG);
  double* infl = (double*)(out + WS_INFL);
  double* mm   = (double*)(out + WS_MM);
  double* dws  = (double*)d_ws;
  float*  nrm  = out + OUT_NORM_OFF;
  float*  stds = out + OUT_STD_OFF;

  scan_kernel<<<M_ROWS/16, 256, 0, stream>>>(feat, mb, sidx, flag);
  refine_kernel<<<M_ROWS, 256, 0, stream>>>(feat, mb, flag, sidx);
  influence_kernel<<<(M_ROWS*64)/256, 256, 0, stream>>>(feat, mb, sidx, infl);
  minmax_kernel<<<1, 1024, 0, stream>>>(infl, mm);
  normstd_kernel<<<(M_ROWS + 255)/256, 256, 0, stream>>>(mm, infl, nrm, stds, dws);
  noise_kernel<<<N_ELEMS/256, 256, 0, stream>>>(feat, stds, out);
  diag_kernel<<<1, 1, 0, stream>>>(dws, out);
  kat_kernel<<<1, 1, 0, stream>>>(out);
}

// Round 10
// 8002.995 us; speedup vs baseline: 2.2081x; 2.2081x over previous
//
#include <hip/hip_runtime.h>
#include <float.h>
#include <math.h>

// ---------------- problem constants ----------------
#define M_ROWS 6272        // 8*28*28 rows of f
#define N_BANK 16384
#define K_DIM  1024
#define HW     784         // 28*28
#define CHW    802816      // 1024*784 (per-batch stride in features)
#define OUT_NORM_OFF 6422528
#define OUT_STD_OFF  6428800
#define N_ELEMS 6422528    // 6272*1024

// f32-scan ambiguity margin on s = ||m||^2 - 2 f.m  (same margin as on d^2)
#define DELTA 0.0625f

#define JSPLIT 16
#define JCHUNK (N_BANK / JSPLIT)   // 1024

// scratch (float offsets in d_out's noised region; all consumed before noise kernel)
#define WS_SIDX 0                      // 6272 ints
#define WS_FLAG 8192                   // 6272 ints
#define WS_INFL 16384                  // 6272 doubles -> 12544 floats
#define WS_MM   28928                  // 2 doubles -> 4 floats
#define WS_MBN  28944                  // 16384 floats
#define WS_PB   45328                  // 16*6272 floats
#define WS_PS   (45328 + 100352)       // 16*6272 floats
#define WS_PI   (45328 + 200704)       // 16*6272 ints

// ---------------- threefry2x32-20, generalized key ----------------
__device__ __forceinline__ unsigned rotl32(unsigned v, int r){ return (v << r) | (v >> (32 - r)); }

__device__ __forceinline__ void tf2x32(unsigned k0, unsigned k1, unsigned x0, unsigned x1,
                                       unsigned& o0, unsigned& o1){
  const unsigned ks2 = k0 ^ k1 ^ 0x1BD11BDAu;
  x0 += k0; x1 += k1;
#define TF_ROUND(rot) { x0 += x1; x1 = rotl32(x1, rot); x1 ^= x0; }
  TF_ROUND(13) TF_ROUND(15) TF_ROUND(26) TF_ROUND(6)
  x0 += k1;  x1 += ks2 + 1u;
  TF_ROUND(17) TF_ROUND(29) TF_ROUND(16) TF_ROUND(24)
  x0 += ks2; x1 += k0 + 2u;
  TF_ROUND(13) TF_ROUND(15) TF_ROUND(26) TF_ROUND(6)
  x0 += k0;  x1 += k1 + 3u;
  TF_ROUND(17) TF_ROUND(29) TF_ROUND(16) TF_ROUND(24)
  x0 += k1;  x1 += ks2 + 4u;
  TF_ROUND(13) TF_ROUND(15) TF_ROUND(26) TF_ROUND(6)
  x0 += ks2; x1 += k0 + 5u;
#undef TF_ROUND
  o0 = x0; o1 = x1;
}

// JAX uniform-from-bits + XLA ErfInv32 (Giles), scaled by sqrt(2)
__device__ __forceinline__ float normal_from_bits(unsigned bits){
  unsigned fb = (bits >> 9) | 0x3F800000u;
  float f = __uint_as_float(fb) - 1.0f;            // [0, 1)
  const float lo = __uint_as_float(0xBF7FFFFFu);   // nextafter(-1,0)
  float u = fmaxf(lo, f * 2.0f + lo);
  float w = -log1pf(-u * u);
  float p;
  if (w < 5.0f){
    w = w - 2.5f;
    p = 2.81022636e-08f;
    p = fmaf(p, w, 3.43273939e-07f);
    p = fmaf(p, w, -3.5233877e-06f);
    p = fmaf(p, w, -4.39150654e-06f);
    p = fmaf(p, w, 0.00021858087f);
    p = fmaf(p, w, -0.00125372503f);
    p = fmaf(p, w, -0.00417768164f);
    p = fmaf(p, w, 0.246640727f);
    p = fmaf(p, w, 1.50140941f);
  } else {
    w = sqrtf(w) - 3.0f;
    p = -0.000200214257f;
    p = fmaf(p, w, 0.000100950558f);
    p = fmaf(p, w, 0.00134934322f);
    p = fmaf(p, w, -0.00367342844f);
    p = fmaf(p, w, 0.00573950773f);
    p = fmaf(p, w, -0.0076224613f);
    p = fmaf(p, w, 0.00943887047f);
    p = fmaf(p, w, 1.00167406f);
    p = fmaf(p, w, 2.83297682f);
  }
  return 1.41421356237f * (p * u);
}

// ---------------- kernel 0: ||m_j||^2, one wave per bank row ----------------
__global__ __launch_bounds__(256) void mbnorm_kernel(const float* __restrict__ mb, float* __restrict__ mbn){
  int wid  = (blockIdx.x * 256 + threadIdx.x) >> 6;
  int lane = threadIdx.x & 63;
  if (wid >= N_BANK) return;
  const float* row = mb + (size_t)wid * K_DIM;
  float s = 0.f;
#pragma unroll
  for (int i = 0; i < 16; ++i){ float v = row[lane + i*64]; s = fmaf(v, v, s); }
#pragma unroll
  for (int off = 32; off; off >>= 1) s += __shfl_down(s, off);
  if (lane == 0) mbn[wid] = s;
}

// ---------------- kernel A: tiled GEMM with running top-2 min of s = ||m||^2 - 2 f.m ----------
// 64x64 tile, 4x4 acc/thread, no cross-lane reduction in the K-loop.
__global__ __launch_bounds__(256) void knn_min_kernel(
    const float* __restrict__ feat, const float* __restrict__ mb,
    const float* __restrict__ mbn,
    float* __restrict__ pbest, float* __restrict__ psec, int* __restrict__ pidx)
{
  __shared__ float As[32][64];       // [k][row]
  __shared__ float Bs[32][68];       // [k][j], stride 68 (272B rows, 16B-aligned)
  __shared__ float rb[64][17];
  __shared__ float rs[64][17];
  __shared__ int   ri[64][17];

  const int t  = threadIdx.x;
  const int tx = t & 15;             // j micro-tile
  const int ty = t >> 4;             // row micro-tile
  const int r0 = blockIdx.x * 64;
  const int j0base = blockIdx.y * JCHUNK;

  // A-load: thread owns row mA, 8 k-slices per stage
  const int mA = t & 63;
  const int kA = t >> 6;             // 0..3
  const int rA = r0 + mA;
  const int bA = rA / HW;
  const int baseA = bA * CHW + (rA - bA * HW);
  // B-load: thread owns k=kB, 8 j-slices per stage
  const int kB = t & 31;
  const int jB = t >> 5;             // 0..7

  float best[4], sec[4]; int bidx[4];
#pragma unroll
  for (int i = 0; i < 4; ++i){ best[i] = FLT_MAX; sec[i] = FLT_MAX; bidx[i] = 0; }

  for (int jt = 0; jt < JCHUNK; jt += 64){
    const int j0 = j0base + jt;
    float acc[4][4];
#pragma unroll
    for (int i = 0; i < 4; ++i)
#pragma unroll
      for (int j = 0; j < 4; ++j) acc[i][j] = 0.f;

    for (int k0 = 0; k0 < K_DIM; k0 += 32){
#pragma unroll
      for (int i = 0; i < 8; ++i){
        int kk = kA + i*4;
        As[kk][mA] = feat[baseA + (k0 + kk) * HW];
      }
#pragma unroll
      for (int i = 0; i < 8; ++i){
        int j = jB + i*8;
        Bs[kB][j] = mb[(size_t)(j0 + j) * K_DIM + k0 + kB];
      }
      __syncthreads();
#pragma unroll
      for (int kk = 0; kk < 32; ++kk){
        const float4 a  = *reinterpret_cast<const float4*>(&As[kk][ty*4]);
        const float4 bq = *reinterpret_cast<const float4*>(&Bs[kk][tx*4]);
        float av[4] = {a.x, a.y, a.z, a.w};
        float bv[4] = {bq.x, bq.y, bq.z, bq.w};
#pragma unroll
        for (int i = 0; i < 4; ++i)
#pragma unroll
          for (int j = 0; j < 4; ++j)
            acc[i][j] = fmaf(av[i], bv[j], acc[i][j]);
      }
      __syncthreads();
    }
#pragma unroll
    for (int i = 0; i < 4; ++i)
#pragma unroll
      for (int jj = 0; jj < 4; ++jj){
        int j = j0 + tx*4 + jj;
        float s = fmaf(-2.0f, acc[i][jj], mbn[j]);
        if (s < best[i]){ sec[i] = best[i]; best[i] = s; bidx[i] = j; }
        else if (s < sec[i]){ sec[i] = s; }
      }
  }

  // block reduction across the 16 tx-columns per row
#pragma unroll
  for (int i = 0; i < 4; ++i){
    rb[ty*4+i][tx] = best[i]; rs[ty*4+i][tx] = sec[i]; ri[ty*4+i][tx] = bidx[i];
  }
  __syncthreads();
  if (t < 64){
    float gb = FLT_MAX, gs = FLT_MAX; int gi = 0;
#pragma unroll
    for (int x = 0; x < 16; ++x){
      float v = rb[t][x], s2 = rs[t][x]; int ii = ri[t][x];
      if (v < gb){ gs = fminf(gb, s2); gb = v; gi = ii; }
      else { gs = fminf(gs, v); }
    }
    pbest[blockIdx.y * M_ROWS + r0 + t] = gb;
    psec [blockIdx.y * M_ROWS + r0 + t] = gs;
    pidx [blockIdx.y * M_ROWS + r0 + t] = gi;
  }
}

// ---------------- kernel B: combine JSPLIT partials -> argmin idx + ambiguity flag ----------
__global__ __launch_bounds__(256) void reduce_parts_kernel(
    const float* __restrict__ pbest, const float* __restrict__ psec, const int* __restrict__ pidx,
    int* __restrict__ sidx, int* __restrict__ flag)
{
  int r = blockIdx.x * blockDim.x + threadIdx.x;
  if (r >= M_ROWS) return;
  float gb = FLT_MAX, gs = FLT_MAX; int gi = 0;
#pragma unroll
  for (int p = 0; p < JSPLIT; ++p){
    float v = pbest[p * M_ROWS + r], s2 = psec[p * M_ROWS + r]; int ii = pidx[p * M_ROWS + r];
    if (v < gb){ gs = fminf(gb, s2); gb = v; gi = ii; }
    else { gs = fminf(gs, v); }
  }
  sidx[r] = gi;
  flag[r] = (gs - gb < DELTA) ? 1 : 0;
}

// ---------------- kernel C: f64 full re-scan for ambiguous rows ----------------
__global__ __launch_bounds__(256) void refine_kernel(
    const float* __restrict__ feat, const float* __restrict__ mb,
    const int* __restrict__ flag, int* __restrict__ sidx)
{
  const int r = blockIdx.x;
  if (!flag[r]) return;
  __shared__ float fs[K_DIM];
  const int b = r / HW, hw = r - b * HW;
  for (int c = threadIdx.x; c < K_DIM; c += 256) fs[c] = feat[b * CHW + c * HW + hw];
  __syncthreads();

  double bestv = DBL_MAX; int bi = N_BANK - 1;
  for (int j = threadIdx.x; j < N_BANK; j += 256){
    const float* mrow = mb + (size_t)j * K_DIM;
    double s = 0.0;
#pragma unroll 8
    for (int c = 0; c < K_DIM; ++c){
      double d = (double)fs[c] - (double)mrow[c];
      s = fma(d, d, s);
    }
    if (s < bestv){ bestv = s; bi = j; }
  }
  __shared__ double rv[256]; __shared__ int ri2[256];
  rv[threadIdx.x] = bestv; ri2[threadIdx.x] = bi; __syncthreads();
  for (int off = 128; off; off >>= 1){
    if (threadIdx.x < off){
      double v2 = rv[threadIdx.x + off]; int i2 = ri2[threadIdx.x + off];
      if (v2 < rv[threadIdx.x] || (v2 == rv[threadIdx.x] && i2 < ri2[threadIdx.x])){
        rv[threadIdx.x] = v2; ri2[threadIdx.x] = i2;
      }
    }
    __syncthreads();
  }
  if (threadIdx.x == 0) sidx[r] = ri2[0];
}

// ---------------- kernel D: f64 influence from the winner ----------------
__global__ __launch_bounds__(256) void influence_kernel(
    const float* __restrict__ feat, const float* __restrict__ mb,
    const int* __restrict__ sidx, double* __restrict__ infl)
{
  const int wid  = (blockIdx.x * 256 + threadIdx.x) >> 6;
  const int lane = threadIdx.x & 63;
  if (wid >= M_ROWS) return;
  const int r = wid;
  const int b = r / HW;
  const int baseR = b * CHW + (r - b * HW);
  const float* mrow = mb + (size_t)sidx[r] * K_DIM;
  double sabs = 0.0, sd2 = 0.0;
#pragma unroll
  for (int i = 0; i < 16; ++i){
    int c = lane + i*64;
    double d = (double)feat[baseR + c * HW] - (double)mrow[c];
    sd2  = fma(d, d, sd2);
    sabs += fabs(d);
  }
#pragma unroll
  for (int off = 1; off < 64; off <<= 1){
    sabs += __shfl_xor(sabs, off);
    sd2  += __shfl_xor(sd2, off);
  }
  if (lane == 0){
    double dist = sqrt(fmax(sd2, 0.0) + 1e-8);
    infl[r] = (sabs / 1024.0) / (dist + 1e-8);
  }
}

// ---------------- kernel E: f64 global min/max ----------------
__global__ __launch_bounds__(1024) void minmax_kernel(const double* __restrict__ infl, double* __restrict__ mm){
  __shared__ double smn[1024], smx[1024];
  int t = threadIdx.x;
  double mn = DBL_MAX, mx = -DBL_MAX;
  for (int i = t; i < M_ROWS; i += 1024){ double v = infl[i]; mn = fmin(mn, v); mx = fmax(mx, v); }
  smn[t] = mn; smx[t] = mx; __syncthreads();
  for (int off = 512; off > 0; off >>= 1){
    if (t < off){ smn[t] = fmin(smn[t], smn[t+off]); smx[t] = fmax(smx[t], smx[t+off]); }
    __syncthreads();
  }
  if (t == 0){ mm[0] = smn[0]; mm[1] = smx[0]; }
}

// ---------------- kernel F: f64 norm + std -> f32 outputs; stash mm into d_ws ----------------
__global__ __launch_bounds__(256) void normstd_kernel(
    const double* __restrict__ mm, const double* __restrict__ infl,
    float* __restrict__ norm_out, float* __restrict__ std_out, double* __restrict__ dws)
{
  int r = blockIdx.x * blockDim.x + threadIdx.x;
  if (r >= M_ROWS) return;
  double imin = mm[0], imax = mm[1];
  if (r == 0){ dws[0] = imin; dws[1] = imax; }
  double rng = imax - imin;
  double nrm = (rng > 1e-8) ? (infl[r] - imin) / rng : 0.0;
  norm_out[r] = (float)nrm;
  std_out[r]  = (float)(0.01 + nrm * 0.49);
}

// ---------------- kernel G: noise — partitionable (0,e), bits = o0 ^ o1 (VERIFIED r9) ------
__global__ __launch_bounds__(256) void noise_kernel(
    const float* __restrict__ feat, const float* __restrict__ stds, float* __restrict__ out)
{
  int tid = blockIdx.x * 256 + threadIdx.x;     // BCHW address
  int b   = tid / CHW;
  int rem = tid - b * CHW;
  int c   = rem / HW;
  int hw  = rem - c * HW;
  int r   = b * HW + hw;                        // row in (6272, 1024) view
  unsigned e = (unsigned)r * (unsigned)K_DIM + (unsigned)c;
  unsigned o0, o1;
  tf2x32(0u, 1u, 0u, e, o0, o1);
  unsigned bits = o0 ^ o1;
  float n = normal_from_bits(bits);
  out[tid] = feat[tid] + n * stds[r];
}

// ---------------- diagnostics (inert when healthy; kept as regression tripwires) ----------
__global__ void diag_kernel(const double* __restrict__ dws, float* __restrict__ out){
  double imin = dws[0], imax = dws[1];
  double rng = imax - imin;
  double code = 0.0, payload = 0.0;
  if (!(imin == imin) || !(imax == imax)){ code = 5e6; }
  else if (rng <= 1e-8){ code = 1e6; payload = fmin(fmax(rng, 0.0) * 1e12, 9e5); }
  else if (imax > 0.5){ code = 2e6; payload = fmin(imax * 1e4, 9e5); }
  else if (imin <= 1e-4){ code = 3e6; payload = fmin(fmax(imin, 0.0) * 1e6, 9e5); }
  else if (imax > 10.0 * imin){ code = 4e6; payload = fmin(imax * 1e4, 9e5); }
  if (code > 0.0) out[0] = (float)(code + payload);
}

__global__ void kat_kernel(float* __restrict__ out){
  float code = 0.f;
  unsigned a, b;
  tf2x32(0u, 0u, 0u, 0u, a, b);
  if (a != 0x6b200159u || b != 0x99ba4efeu) code = 1e10f;
  unsigned c2, d2;
  tf2x32(0x13198a2eu, 0x03707344u, 0x243f6a88u, 0x85a308d3u, c2, d2);
  if (code == 0.f && (c2 != 0xc4923a9cu || d2 != 0x483df7a0u)) code = 3e9f;
  float n = normal_from_bits(0x6b200159u);
  if (code == 0.f && fabsf(n - (-0.20584226f)) > 2e-5f) code = 1e9f;
  if (code > 0.f) out[0] = code;
}

extern "C" void kernel_launch(void* const* d_in, const int* in_sizes, int n_in,
                              void* d_out, int out_size, void* d_ws, size_t ws_size,
                              hipStream_t stream) {
  const float* feat = (const float*)d_in[0];
  const float* mb   = (const float*)d_in[1];
  float* out = (float*)d_out;

  int*    sidx  = (int*)(out + WS_SIDX);
  int*    flag  = (int*)(out + WS_FLAG);
  double* infl  = (double*)(out + WS_INFL);
  double* mm    = (double*)(out + WS_MM);
  float*  mbn   = out + WS_MBN;
  float*  pb    = out + WS_PB;
  float*  ps    = out + WS_PS;
  int*    pi    = (int*)(out + WS_PI);
  double* dws   = (double*)d_ws;
  float*  nrm   = out + OUT_NORM_OFF;
  float*  stds  = out + OUT_STD_OFF;

  mbnorm_kernel<<<N_BANK/4, 256, 0, stream>>>(mb, mbn);
  knn_min_kernel<<<dim3(M_ROWS/64, JSPLIT), 256, 0, stream>>>(feat, mb, mbn, pb, ps, pi);
  reduce_parts_kernel<<<(M_ROWS + 255)/256, 256, 0, stream>>>(pb, ps, pi, sidx, flag);
  refine_kernel<<<M_ROWS, 256, 0, stream>>>(feat, mb, flag, sidx);
  influence_kernel<<<(M_ROWS*64)/256, 256, 0, stream>>>(feat, mb, sidx, infl);
  minmax_kernel<<<1, 1024, 0, stream>>>(infl, mm);
  normstd_kernel<<<(M_ROWS + 255)/256, 256, 0, stream>>>(mm, infl, nrm, stds, dws);
  noise_kernel<<<N_ELEMS/256, 256, 0, stream>>>(feat, stds, out);
  diag_kernel<<<1, 1, 0, stream>>>(dws, out);
  kat_kernel<<<1, 1, 0, stream>>>(out);
}

// Round 11
// 3203.595 us; speedup vs baseline: 5.5161x; 2.4981x over previous
//
#include <hip/hip_runtime.h>
#include <float.h>
#include <math.h>

// ---------------- problem constants ----------------
#define M_ROWS 6272        // 8*28*28 rows of f
#define N_BANK 16384
#define K_DIM  1024
#define HW     784         // 28*28
#define CHW    802816      // 1024*784 (per-batch stride in features)
#define OUT_NORM_OFF 6422528
#define OUT_STD_OFF  6428800
#define N_ELEMS 6422528    // 6272*1024

#define DELTA 0.0625f      // f32-scan ambiguity margin on s = ||m||^2 - 2 f.m
#define JSPLIT 32
#define JCHUNK (N_BANK / JSPLIT)   // 512
#define CAP 1024           // max refined rows (expected ~5-20)

// scratch layout (float offsets in d_out's noised region; all consumed before noise kernel)
#define WS_SIDX 0                  // 6272 ints
#define WS_INFL 8192               // 6272 doubles = 12544 floats
#define WS_MM   20736              // 2 doubles = 4 floats
#define WS_MBN  20744              // 16384 floats
#define WS_PB   40960              // 32*6272 floats
#define WS_PS   241664             // 32*6272
#define WS_PI   442368             // 32*6272 ints
#define WS_LIST 643072             // CAP ints
#define WS_RPV  644096             // CAP*64 doubles = 131072 floats (even offset: f64-aligned)
#define WS_RPI  775168             // CAP*64 ints

// ---------------- threefry2x32-20, generalized key ----------------
__device__ __forceinline__ unsigned rotl32(unsigned v, int r){ return (v << r) | (v >> (32 - r)); }

__device__ __forceinline__ void tf2x32(unsigned k0, unsigned k1, unsigned x0, unsigned x1,
                                       unsigned& o0, unsigned& o1){
  const unsigned ks2 = k0 ^ k1 ^ 0x1BD11BDAu;
  x0 += k0; x1 += k1;
#define TF_ROUND(rot) { x0 += x1; x1 = rotl32(x1, rot); x1 ^= x0; }
  TF_ROUND(13) TF_ROUND(15) TF_ROUND(26) TF_ROUND(6)
  x0 += k1;  x1 += ks2 + 1u;
  TF_ROUND(17) TF_ROUND(29) TF_ROUND(16) TF_ROUND(24)
  x0 += ks2; x1 += k0 + 2u;
  TF_ROUND(13) TF_ROUND(15) TF_ROUND(26) TF_ROUND(6)
  x0 += k0;  x1 += k1 + 3u;
  TF_ROUND(17) TF_ROUND(29) TF_ROUND(16) TF_ROUND(24)
  x0 += k1;  x1 += ks2 + 4u;
  TF_ROUND(13) TF_ROUND(15) TF_ROUND(26) TF_ROUND(6)
  x0 += ks2; x1 += k0 + 5u;
#undef TF_ROUND
  o0 = x0; o1 = x1;
}

// JAX uniform-from-bits + XLA ErfInv32 (Giles), scaled by sqrt(2)
__device__ __forceinline__ float normal_from_bits(unsigned bits){
  unsigned fb = (bits >> 9) | 0x3F800000u;
  float f = __uint_as_float(fb) - 1.0f;
  const float lo = __uint_as_float(0xBF7FFFFFu);
  float u = fmaxf(lo, f * 2.0f + lo);
  float w = -log1pf(-u * u);
  float p;
  if (w < 5.0f){
    w = w - 2.5f;
    p = 2.81022636e-08f;
    p = fmaf(p, w, 3.43273939e-07f);
    p = fmaf(p, w, -3.5233877e-06f);
    p = fmaf(p, w, -4.39150654e-06f);
    p = fmaf(p, w, 0.00021858087f);
    p = fmaf(p, w, -0.00125372503f);
    p = fmaf(p, w, -0.00417768164f);
    p = fmaf(p, w, 0.246640727f);
    p = fmaf(p, w, 1.50140941f);
  } else {
    w = sqrtf(w) - 3.0f;
    p = -0.000200214257f;
    p = fmaf(p, w, 0.000100950558f);
    p = fmaf(p, w, 0.00134934322f);
    p = fmaf(p, w, -0.00367342844f);
    p = fmaf(p, w, 0.00573950773f);
    p = fmaf(p, w, -0.0076224613f);
    p = fmaf(p, w, 0.00943887047f);
    p = fmaf(p, w, 1.00167406f);
    p = fmaf(p, w, 2.83297682f);
  }
  return 1.41421356237f * (p * u);
}

// ---------------- kernel 0: ||m_j||^2 ----------------
__global__ __launch_bounds__(256) void mbnorm_kernel(const float* __restrict__ mb, float* __restrict__ mbn){
  int wid  = (blockIdx.x * 256 + threadIdx.x) >> 6;
  int lane = threadIdx.x & 63;
  if (wid >= N_BANK) return;
  const float* row = mb + (size_t)wid * K_DIM;
  float s = 0.f;
#pragma unroll
  for (int i = 0; i < 16; ++i){ float v = row[lane + i*64]; s = fmaf(v, v, s); }
#pragma unroll
  for (int off = 32; off; off >>= 1) s += __shfl_down(s, off);
  if (lane == 0) mbn[wid] = s;
}

// ---------------- init: zero the refine-list counter (d_ws byte 16) ----------------
__global__ void init_kernel(int* __restrict__ cnt){ if (threadIdx.x == 0) *cnt = 0; }

// ---------------- kernel A: 128x128 tiled GEMM, running top-2 min of s ----------------
__global__ __launch_bounds__(256) void knn_min_kernel(
    const float* __restrict__ feat, const float* __restrict__ mb,
    const float* __restrict__ mbn,
    float* __restrict__ pbest, float* __restrict__ psec, int* __restrict__ pidx)
{
  __shared__ float smem[8320];         // As[32][128] | Bs[32][132]
  float* As = smem;                    // [kk*128 + m]
  float* Bs = smem + 4096;             // [kk*132 + j]

  const int t  = threadIdx.x;
  const int tx = t & 15;
  const int ty = t >> 4;
  const int r0 = blockIdx.x * 128;
  const int j0base = blockIdx.y * JCHUNK;

  const int mA = t & 127;              // A loader: row
  const int kA = t >> 7;               // 0..1
  const int rA = r0 + mA;
  const int bA = rA / HW;
  const int baseA = bA * CHW + (rA - bA * HW);
  const int kB = t & 31;               // B loader: k
  const int jB = t >> 5;               // 0..7

  float best[8], sec[8]; int bidx[8];
#pragma unroll
  for (int i = 0; i < 8; ++i){ best[i] = FLT_MAX; sec[i] = FLT_MAX; bidx[i] = 0; }

  for (int jt = 0; jt < JCHUNK; jt += 128){
    const int j0 = j0base + jt;
    float acc[8][8];
#pragma unroll
    for (int i = 0; i < 8; ++i)
#pragma unroll
      for (int j = 0; j < 8; ++j) acc[i][j] = 0.f;

    for (int k0 = 0; k0 < K_DIM; k0 += 32){
#pragma unroll
      for (int i = 0; i < 16; ++i){
        int kk = kA + 2*i;
        As[kk*128 + mA] = feat[baseA + (k0 + kk) * HW];
      }
#pragma unroll
      for (int i = 0; i < 16; ++i){
        int j = jB + 8*i;
        Bs[kB*132 + j] = mb[(size_t)(j0 + j) * K_DIM + k0 + kB];
      }
      __syncthreads();
#pragma unroll
      for (int kk = 0; kk < 32; ++kk){
        const float4 a0 = *reinterpret_cast<const float4*>(&As[kk*128 + ty*4]);
        const float4 a1 = *reinterpret_cast<const float4*>(&As[kk*128 + ty*4 + 64]);
        const float4 b0 = *reinterpret_cast<const float4*>(&Bs[kk*132 + tx*4]);
        const float4 b1 = *reinterpret_cast<const float4*>(&Bs[kk*132 + tx*4 + 64]);
        const float av[8] = {a0.x,a0.y,a0.z,a0.w, a1.x,a1.y,a1.z,a1.w};
        const float bv[8] = {b0.x,b0.y,b0.z,b0.w, b1.x,b1.y,b1.z,b1.w};
#pragma unroll
        for (int i = 0; i < 8; ++i)
#pragma unroll
          for (int j = 0; j < 8; ++j)
            acc[i][j] = fmaf(av[i], bv[j], acc[i][j]);
      }
      __syncthreads();
    }
    // fold this j-panel into per-row-slot top-2
#pragma unroll
    for (int i = 0; i < 8; ++i)
#pragma unroll
      for (int cj = 0; cj < 2; ++cj)
#pragma unroll
        for (int jj = 0; jj < 4; ++jj){
          int j = j0 + tx*4 + cj*64 + jj;
          float s = fmaf(-2.0f, acc[i][cj*4 + jj], mbn[j]);
          if (s < best[i]){ sec[i] = best[i]; best[i] = s; bidx[i] = j; }
          else if (s < sec[i]){ sec[i] = s; }
        }
  }

  // block reduction across the 16 tx columns (reuse smem)
  __syncthreads();
  float* rb = smem;                    // [128][17]
  float* rs = smem + 2176;
  int*   ri = (int*)(smem + 4352);
#pragma unroll
  for (int i = 0; i < 8; ++i){
    int row = ty*4 + (i>>2)*64 + (i&3);
    rb[row*17 + tx] = best[i]; rs[row*17 + tx] = sec[i]; ri[row*17 + tx] = bidx[i];
  }
  __syncthreads();
  if (t < 128){
    float gb = FLT_MAX, gs = FLT_MAX; int gi = 0;
#pragma unroll
    for (int x = 0; x < 16; ++x){
      float v = rb[t*17 + x], s2 = rs[t*17 + x]; int ii = ri[t*17 + x];
      if (v < gb){ gs = fminf(gb, s2); gb = v; gi = ii; }
      else { gs = fminf(gs, v); }
    }
    pbest[blockIdx.y * M_ROWS + r0 + t] = gb;
    psec [blockIdx.y * M_ROWS + r0 + t] = gs;
    pidx [blockIdx.y * M_ROWS + r0 + t] = gi;
  }
}

// ---------------- kernel B: combine partials -> sidx + compact ambiguous list ----------
__global__ __launch_bounds__(256) void reduce_parts_kernel(
    const float* __restrict__ pbest, const float* __restrict__ psec, const int* __restrict__ pidx,
    int* __restrict__ sidx, int* __restrict__ list, int* __restrict__ cnt)
{
  int r = blockIdx.x * blockDim.x + threadIdx.x;
  if (r >= M_ROWS) return;
  float gb = FLT_MAX, gs = FLT_MAX; int gi = 0;
#pragma unroll
  for (int p = 0; p < JSPLIT; ++p){
    float v = pbest[p * M_ROWS + r], s2 = psec[p * M_ROWS + r]; int ii = pidx[p * M_ROWS + r];
    if (v < gb){ gs = fminf(gb, s2); gb = v; gi = ii; }
    else { gs = fminf(gs, v); }
  }
  sidx[r] = gi;
  if (gs - gb < DELTA){
    int pos = atomicAdd(cnt, 1);
    if (pos < CAP) list[pos] = r;
  }
}

// ---------------- kernel C1: f64 partial re-scan (row, 256-bank-chunk) work items --------
__global__ __launch_bounds__(256) void refine_part_kernel(
    const float* __restrict__ feat, const float* __restrict__ mb,
    const int* __restrict__ list, const int* __restrict__ cnt,
    double* __restrict__ rpv, int* __restrict__ rpi)
{
  __shared__ float fs[K_DIM];
  __shared__ double wvv[4]; __shared__ int wvi[4];
  const int nf = min(*cnt, CAP);
  const int nwork = nf * 64;
  const int wv = threadIdx.x >> 6, lane = threadIdx.x & 63;

  for (int w = blockIdx.x; w < nwork; w += gridDim.x){
    const int fi = w >> 6, chunk = w & 63;
    const int r = list[fi];
    const int b = r / HW, hw = r - b * HW;
    for (int c = threadIdx.x; c < K_DIM; c += 256) fs[c] = feat[b * CHW + c * HW + hw];
    __syncthreads();

    double bv = DBL_MAX; int bi = N_BANK;
    for (int rr = 0; rr < 64; ++rr){
      int j = chunk * 256 + wv * 64 + rr;
      const float* mrow = mb + (size_t)j * K_DIM;
      double s = 0.0;
#pragma unroll
      for (int i = 0; i < 16; ++i){
        int c = lane + i * 64;
        double d = (double)fs[c] - (double)mrow[c];
        s = fma(d, d, s);
      }
#pragma unroll
      for (int off = 1; off < 64; off <<= 1) s += __shfl_xor(s, off);
      if (s < bv){ bv = s; bi = j; }       // j ascending -> lowest idx on ties
    }
    if (lane == 0){ wvv[wv] = bv; wvi[wv] = bi; }
    __syncthreads();
    if (threadIdx.x == 0){
      double gv = wvv[0]; int gi2 = wvi[0];
#pragma unroll
      for (int x = 1; x < 4; ++x){
        if (wvv[x] < gv || (wvv[x] == gv && wvi[x] < gi2)){ gv = wvv[x]; gi2 = wvi[x]; }
      }
      rpv[fi * 64 + chunk] = gv; rpi[fi * 64 + chunk] = gi2;
    }
    __syncthreads();
  }
}

// ---------------- kernel C2: combine 64 chunk-partials per refined row ----------------
__global__ __launch_bounds__(256) void refine_combine_kernel(
    const double* __restrict__ rpv, const int* __restrict__ rpi,
    const int* __restrict__ list, const int* __restrict__ cnt, int* __restrict__ sidx)
{
  const int nf = min(*cnt, CAP);
  const int wv = threadIdx.x >> 6, lane = threadIdx.x & 63;
  for (int fi = wv; fi < nf; fi += 4){
    double v = rpv[fi * 64 + lane]; int ii = rpi[fi * 64 + lane];
#pragma unroll
    for (int off = 1; off < 64; off <<= 1){
      double ov = __shfl_xor(v, off); int oi = __shfl_xor(ii, off);
      if (ov < v || (ov == v && oi < ii)){ v = ov; ii = oi; }
    }
    if (lane == 0) sidx[list[fi]] = ii;
  }
}

// ---------------- kernel D: f64 influence from the winner ----------------
__global__ __launch_bounds__(256) void influence_kernel(
    const float* __restrict__ feat, const float* __restrict__ mb,
    const int* __restrict__ sidx, double* __restrict__ infl)
{
  const int wid  = (blockIdx.x * 256 + threadIdx.x) >> 6;
  const int lane = threadIdx.x & 63;
  if (wid >= M_ROWS) return;
  const int r = wid;
  const int b = r / HW;
  const int baseR = b * CHW + (r - b * HW);
  const float* mrow = mb + (size_t)sidx[r] * K_DIM;
  double sabs = 0.0, sd2 = 0.0;
#pragma unroll
  for (int i = 0; i < 16; ++i){
    int c = lane + i*64;
    double d = (double)feat[baseR + c * HW] - (double)mrow[c];
    sd2  = fma(d, d, sd2);
    sabs += fabs(d);
  }
#pragma unroll
  for (int off = 1; off < 64; off <<= 1){
    sabs += __shfl_xor(sabs, off);
    sd2  += __shfl_xor(sd2, off);
  }
  if (lane == 0){
    double dist = sqrt(fmax(sd2, 0.0) + 1e-8);
    infl[r] = (sabs / 1024.0) / (dist + 1e-8);
  }
}

// ---------------- kernel E: f64 global min/max ----------------
__global__ __launch_bounds__(1024) void minmax_kernel(const double* __restrict__ infl, double* __restrict__ mm){
  __shared__ double smn[1024], smx[1024];
  int t = threadIdx.x;
  double mn = DBL_MAX, mx = -DBL_MAX;
  for (int i = t; i < M_ROWS; i += 1024){ double v = infl[i]; mn = fmin(mn, v); mx = fmax(mx, v); }
  smn[t] = mn; smx[t] = mx; __syncthreads();
  for (int off = 512; off > 0; off >>= 1){
    if (t < off){ smn[t] = fmin(smn[t], smn[t+off]); smx[t] = fmax(smx[t], smx[t+off]); }
    __syncthreads();
  }
  if (t == 0){ mm[0] = smn[0]; mm[1] = smx[0]; }
}

// ---------------- kernel F: f64 norm + std -> f32; stash mm into d_ws ----------------
__global__ __launch_bounds__(256) void normstd_kernel(
    const double* __restrict__ mm, const double* __restrict__ infl,
    float* __restrict__ norm_out, float* __restrict__ std_out, double* __restrict__ dws)
{
  int r = blockIdx.x * blockDim.x + threadIdx.x;
  if (r >= M_ROWS) return;
  double imin = mm[0], imax = mm[1];
  if (r == 0){ dws[0] = imin; dws[1] = imax; }
  double rng = imax - imin;
  double nrm = (rng > 1e-8) ? (infl[r] - imin) / rng : 0.0;
  norm_out[r] = (float)nrm;
  std_out[r]  = (float)(0.01 + nrm * 0.49);
}

// ---------------- kernel G: noise — partitionable (0,e), bits = o0 ^ o1 (VERIFIED r9) ------
__global__ __launch_bounds__(256) void noise_kernel(
    const float* __restrict__ feat, const float* __restrict__ stds, float* __restrict__ out)
{
  int tid = blockIdx.x * 256 + threadIdx.x;
  int b   = tid / CHW;
  int rem = tid - b * CHW;
  int c   = rem / HW;
  int hw  = rem - c * HW;
  int r   = b * HW + hw;
  unsigned e = (unsigned)r * (unsigned)K_DIM + (unsigned)c;
  unsigned o0, o1;
  tf2x32(0u, 1u, 0u, e, o0, o1);
  unsigned bits = o0 ^ o1;
  float n = normal_from_bits(bits);
  out[tid] = feat[tid] + n * stds[r];
}

// ---------------- diagnostics (inert when healthy) ----------------
__global__ void diag_kernel(const double* __restrict__ dws, float* __restrict__ out){
  double imin = dws[0], imax = dws[1];
  double rng = imax - imin;
  double code = 0.0, payload = 0.0;
  if (!(imin == imin) || !(imax == imax)){ code = 5e6; }
  else if (rng <= 1e-8){ code = 1e6; payload = fmin(fmax(rng, 0.0) * 1e12, 9e5); }
  else if (imax > 0.5){ code = 2e6; payload = fmin(imax * 1e4, 9e5); }
  else if (imin <= 1e-4){ code = 3e6; payload = fmin(fmax(imin, 0.0) * 1e6, 9e5); }
  else if (imax > 10.0 * imin){ code = 4e6; payload = fmin(imax * 1e4, 9e5); }
  if (code > 0.0) out[0] = (float)(code + payload);
}

__global__ void kat_kernel(float* __restrict__ out){
  float code = 0.f;
  unsigned a, b;
  tf2x32(0u, 0u, 0u, 0u, a, b);
  if (a != 0x6b200159u || b != 0x99ba4efeu) code = 1e10f;
  unsigned c2, d2;
  tf2x32(0x13198a2eu, 0x03707344u, 0x243f6a88u, 0x85a308d3u, c2, d2);
  if (code == 0.f && (c2 != 0xc4923a9cu || d2 != 0x483df7a0u)) code = 3e9f;
  float n = normal_from_bits(0x6b200159u);
  if (code == 0.f && fabsf(n - (-0.20584226f)) > 2e-5f) code = 1e9f;
  if (code > 0.f) out[0] = code;
}

extern "C" void kernel_launch(void* const* d_in, const int* in_sizes, int n_in,
                              void* d_out, int out_size, void* d_ws, size_t ws_size,
                              hipStream_t stream) {
  const float* feat = (const float*)d_in[0];
  const float* mb   = (const float*)d_in[1];
  float* out = (float*)d_out;

  int*    sidx = (int*)(out + WS_SIDX);
  double* infl = (double*)(out + WS_INFL);
  double* mm   = (double*)(out + WS_MM);
  float*  mbn  = out + WS_MBN;
  float*  pb   = out + WS_PB;
  float*  ps   = out + WS_PS;
  int*    pi   = (int*)(out + WS_PI);
  int*    list = (int*)(out + WS_LIST);
  double* rpv  = (double*)(out + WS_RPV);
  int*    rpi  = (int*)(out + WS_RPI);
  double* dws  = (double*)d_ws;
  int*    cnt  = (int*)((char*)d_ws + 16);
  float*  nrm  = out + OUT_NORM_OFF;
  float*  stds = out + OUT_STD_OFF;

  mbnorm_kernel<<<N_BANK/4, 256, 0, stream>>>(mb, mbn);
  init_kernel<<<1, 64, 0, stream>>>(cnt);
  knn_min_kernel<<<dim3(M_ROWS/128, JSPLIT), 256, 0, stream>>>(feat, mb, mbn, pb, ps, pi);
  reduce_parts_kernel<<<(M_ROWS + 255)/256, 256, 0, stream>>>(pb, ps, pi, sidx, list, cnt);
  refine_part_kernel<<<2048, 256, 0, stream>>>(feat, mb, list, cnt, rpv, rpi);
  refine_combine_kernel<<<1, 256, 0, stream>>>(rpv, rpi, list, cnt, sidx);
  influence_kernel<<<(M_ROWS*64)/256, 256, 0, stream>>>(feat, mb, sidx, infl);
  minmax_kernel<<<1, 1024, 0, stream>>>(infl, mm);
  normstd_kernel<<<(M_ROWS + 255)/256, 256, 0, stream>>>(mm, infl, nrm, stds, dws);
  noise_kernel<<<N_ELEMS/256, 256, 0, stream>>>(feat, stds, out);
  diag_kernel<<<1, 1, 0, stream>>>(dws, out);
  kat_kernel<<<1, 1, 0, stream>>>(out);
}